// Round 2
// baseline (408.737 us; speedup 1.0000x reference)
//
#include <hip/hip_runtime.h>
#include <hip/hip_bf16.h>
#include <stdint.h>

// Problem constants (from reference)
#define IN_F   1024
#define OUT_F  1024
#define NLEAF  16
#define BATCH  4096

// GEMM restructure: k = i*16 + l.  K padded 16384 -> 16512 (16 bias cols
// carrying g / pb, then 112 zero cols) so K % (BK*SPLITK) == 0 with SPLITK=4.
#define KP      16512
#define TM      128
#define TN      128
#define BK      32
#define SPLITK  4
#define KITERS  (KP / (BK * SPLITK))   // 129

typedef __bf16 bf16x8 __attribute__((ext_vector_type(8)));
typedef float  f32x4  __attribute__((ext_vector_type(4)));

#define ASYNC_COPY16(gp, lp)                                                         \
  __builtin_amdgcn_global_load_lds((const __attribute__((address_space(1))) void*)(gp), \
                                   (__attribute__((address_space(3))) void*)(lp),       \
                                   16, 0, 0)

// ---------------------------------------------------------------------------
// Kernel 1: gating softmax.  g[b,l] = softmax_l(x[b,:] @ gw[:,l] + gb[l]).
// One wave per batch row; 4 waves (256 threads) per block.
// ---------------------------------------------------------------------------
__global__ __launch_bounds__(256) void gate_kernel(
    const float* __restrict__ x, const float* __restrict__ gw,
    const float* __restrict__ gb, float* __restrict__ g) {
  const int lane = threadIdx.x & 63;
  const int b = blockIdx.x * 4 + (threadIdx.x >> 6);

  float acc[NLEAF];
#pragma unroll
  for (int l = 0; l < NLEAF; ++l) acc[l] = 0.f;

  const float* xrow = x + b * IN_F;
#pragma unroll 4
  for (int tile = 0; tile < IN_F / 64; ++tile) {
    const int i = lane + tile * 64;
    const float xv = xrow[i];             // coalesced across lanes
    const float* gwp = gw + i * NLEAF;    // 64B row, L1/L2 resident (64 KB total)
#pragma unroll
    for (int l = 0; l < NLEAF; ++l) acc[l] += xv * gwp[l];
  }

  // butterfly reduce each of the 16 sums across the wave
#pragma unroll
  for (int l = 0; l < NLEAF; ++l) {
    float v = acc[l];
#pragma unroll
    for (int off = 32; off > 0; off >>= 1) v += __shfl_xor(v, off, 64);
    acc[l] = v;
  }

  // every lane now holds all 16 logits; softmax redundantly, lanes 0..15 write
  float mx = -1e30f;
#pragma unroll
  for (int l = 0; l < NLEAF; ++l) { acc[l] += gb[l]; mx = fmaxf(mx, acc[l]); }
  float s = 0.f;
  float e[NLEAF];
#pragma unroll
  for (int l = 0; l < NLEAF; ++l) { e[l] = __expf(acc[l] - mx); s += e[l]; }
  const float inv = 1.f / s;
  if (lane < NLEAF) g[b * NLEAF + lane] = e[lane] * inv;
}

// ---------------------------------------------------------------------------
// Kernel 2: pack A.  y[b,k] = bf16( x[b, k>>4] * g[b, k&15] )  for k < 16384,
// then 16 bias cols = g[b,l], then zero cols.  8 elems (16 B) per thread.
// ---------------------------------------------------------------------------
__global__ __launch_bounds__(256) void pack_y_kernel(
    const float* __restrict__ x, const float* __restrict__ g,
    __hip_bfloat16* __restrict__ y) {
  const int b = blockIdx.y;
  const int c = blockIdx.x * blockDim.x + threadIdx.x;
  if (c >= KP / 8) return;
  const int k0 = c * 8;

  __align__(16) __hip_bfloat16 tmp[8];
  if (k0 < IN_F * NLEAF) {
    const float xv = x[b * IN_F + (k0 >> 4)];   // one i per 8-chunk (8 | 16)
    const float* gp = g + b * NLEAF + (k0 & 15);
#pragma unroll
    for (int j = 0; j < 8; ++j) tmp[j] = __float2bfloat16(xv * gp[j]);
  } else {
    const int l0 = k0 - IN_F * NLEAF;
#pragma unroll
    for (int j = 0; j < 8; ++j) {
      const int l = l0 + j;
      tmp[j] = __float2bfloat16(l < NLEAF ? g[b * NLEAF + l] : 0.f);
    }
  }
  *(uint4*)(y + (long)b * KP + k0) = *(const uint4*)tmp;
}

// ---------------------------------------------------------------------------
// Kernel 3: pack B^T.  W[o,k] = bf16(pw[o, k>>4, k&15]) = bf16(pw_flat[o*16384+k])
// (pw row-major IS the [OUT,K] matrix), bias cols = pb[o,l], then zeros.
// ---------------------------------------------------------------------------
__global__ __launch_bounds__(256) void pack_w_kernel(
    const float* __restrict__ pw, const float* __restrict__ pb,
    __hip_bfloat16* __restrict__ W) {
  const int o = blockIdx.y;
  const int c = blockIdx.x * blockDim.x + threadIdx.x;
  if (c >= KP / 8) return;
  const int k0 = c * 8;

  __align__(16) __hip_bfloat16 tmp[8];
  if (k0 < IN_F * NLEAF) {
    const float4* p = (const float4*)(pw + (long)o * (IN_F * NLEAF) + k0);
    const float4 v0 = p[0], v1 = p[1];
    tmp[0] = __float2bfloat16(v0.x); tmp[1] = __float2bfloat16(v0.y);
    tmp[2] = __float2bfloat16(v0.z); tmp[3] = __float2bfloat16(v0.w);
    tmp[4] = __float2bfloat16(v1.x); tmp[5] = __float2bfloat16(v1.y);
    tmp[6] = __float2bfloat16(v1.z); tmp[7] = __float2bfloat16(v1.w);
  } else {
    const int l0 = k0 - IN_F * NLEAF;
#pragma unroll
    for (int j = 0; j < 8; ++j) {
      const int l = l0 + j;
      tmp[j] = __float2bfloat16(l < NLEAF ? pb[o * NLEAF + l] : 0.f);
    }
  }
  *(uint4*)(W + (long)o * KP + k0) = *(const uint4*)tmp;
}

// ---------------------------------------------------------------------------
// Kernel 4: bf16 MFMA GEMM, B^T layout (m97 recipe): 128x128 block tile, BK=32,
// global_load_lds width=16 staging, 4 waves each computing a 64x64 sub-tile
// (4x4 grid of 16x16x32 MFMAs).  Split-K=4 with fp32 atomicAdd epilogue.
//
// LDS K-slot XOR swizzle (R2): naive layout has ds_read_b128 row-stride 64 B
// = 16 banks -> 8 lanes of a quad share one 4-bank group (8-way conflict,
// SQ_LDS_BANK_CONFLICT 1.7e7 in R1).  global_load_lds demands linear LDS
// dest (uniform base + lane*16), so we permute the GLOBAL source slot
// instead: chunk c fetches global k-slot (c&3)^((c>>3)&3).  LDS slot s of
// row r then holds global slot s^((r>>1)&3); the fragment read compensates
// with quad^((r16>>1)&3).  Post-swizzle: lanes 0..7 of a quad cover all 8
// bank groups -> 2-way aliasing only (free per m136).
// ---------------------------------------------------------------------------
__global__ __launch_bounds__(256, 2) void gemm_kernel(
    const __hip_bfloat16* __restrict__ Y,   // [BATCH, KP]
    const __hip_bfloat16* __restrict__ W,   // [OUT_F, KP]
    float* __restrict__ out) {              // [BATCH, OUT_F] (pre-zeroed)
  __shared__ __align__(16) __hip_bfloat16 As[TM * BK];  // 8 KB
  __shared__ __align__(16) __hip_bfloat16 Bs[TN * BK];  // 8 KB

  const int t    = threadIdx.x;
  const int lane = t & 63;
  const int w    = t >> 6;
  const int quad = lane >> 4;
  const int r16  = lane & 15;

  const int m0 = blockIdx.x * TM;
  const int n0 = blockIdx.y * TN;
  const int k0 = blockIdx.z * (KITERS * BK);

  const __hip_bfloat16* aG = Y + (long)m0 * KP + k0;
  const __hip_bfloat16* bG = W + (long)n0 * KP + k0;

  // staging: 8 KB per tile = 512 16-byte chunks; chunk c -> row c>>2, LDS
  // 16B-slot c&3, GLOBAL 16B-slot (c&3)^((c>>3)&3)  (K-slot XOR swizzle).
  const int  c0 = t, c1 = t + 256;
  const int  sl0 = (c0 & 3) ^ ((c0 >> 3) & 3);
  const int  sl1 = (c1 & 3) ^ ((c1 >> 3) & 3);
  const long aOff0 = (long)(c0 >> 2) * KP + sl0 * 8;  // elements
  const long aOff1 = (long)(c1 >> 2) * KP + sl1 * 8;

  const int wm = (w >> 1) * 64;
  const int wn = (w & 1) * 64;
  const int swz = (r16 >> 1) & 3;   // read-side swizzle compensation

  f32x4 acc[4][4] = {};

  for (int it = 0; it < KITERS; ++it) {
    ASYNC_COPY16(aG + aOff0, (char*)As + c0 * 16);
    ASYNC_COPY16(aG + aOff1, (char*)As + c1 * 16);
    ASYNC_COPY16(bG + aOff0, (char*)Bs + c0 * 16);
    ASYNC_COPY16(bG + aOff1, (char*)Bs + c1 * 16);
    __syncthreads();  // compiler emits vmcnt(0) drain before s_barrier

    bf16x8 af[4], bfr[4];
    // A frag: A[m = r16][k = quad*8 + j] ; B frag symmetric for B^T operand
#pragma unroll
    for (int mi = 0; mi < 4; ++mi)
      af[mi] = *(const bf16x8*)(As + (wm + mi * 16 + r16) * BK + (quad ^ swz) * 8);
#pragma unroll
    for (int ni = 0; ni < 4; ++ni)
      bfr[ni] = *(const bf16x8*)(Bs + (wn + ni * 16 + r16) * BK + (quad ^ swz) * 8);

#pragma unroll
    for (int mi = 0; mi < 4; ++mi)
#pragma unroll
      for (int ni = 0; ni < 4; ++ni)
        acc[mi][ni] = __builtin_amdgcn_mfma_f32_16x16x32_bf16(
            af[mi], bfr[ni], acc[mi][ni], 0, 0, 0);

    __syncthreads();
    aG += BK;
    bG += BK;
  }

  // Epilogue: C/D layout col = lane&15, row = quad*4 + reg  [learn_hip m89/m91]
#pragma unroll
  for (int mi = 0; mi < 4; ++mi)
#pragma unroll
    for (int ni = 0; ni < 4; ++ni)
#pragma unroll
      for (int r = 0; r < 4; ++r) {
        const int row = m0 + wm + mi * 16 + quad * 4 + r;
        const int col = n0 + wn + ni * 16 + r16;
        atomicAdd(out + (long)row * OUT_F + col, acc[mi][ni][r]);
      }
}

// ---------------------------------------------------------------------------
// Fallback (ws too small for packed buffers): slow but correct fp32 path.
// ---------------------------------------------------------------------------
__global__ __launch_bounds__(256) void fallback_kernel(
    const float* __restrict__ x, const float* __restrict__ pw,
    const float* __restrict__ pb, const float* __restrict__ g,
    float* __restrict__ out) {
  const int b = blockIdx.x;
  __shared__ float xs[IN_F];
  __shared__ float gs[NLEAF];
  const int t = threadIdx.x;
  for (int j = t; j < IN_F; j += 256) xs[j] = x[(long)b * IN_F + j];
  if (t < NLEAF) gs[t] = g[b * NLEAF + t];
  __syncthreads();
  for (int o = t; o < OUT_F; o += 256) {
    const float* pwo = pw + (long)o * (IN_F * NLEAF);
    float acc = 0.f;
    for (int i = 0; i < IN_F; ++i) {
      const float xv = xs[i];
      float wsum = 0.f;
#pragma unroll
      for (int l = 0; l < NLEAF; ++l) wsum += gs[l] * pwo[i * NLEAF + l];
      acc += xv * wsum;
    }
    float bias = 0.f;
#pragma unroll
    for (int l = 0; l < NLEAF; ++l) bias += gs[l] * pb[o * NLEAF + l];
    out[(long)b * OUT_F + o] = acc + bias;
  }
}

extern "C" void kernel_launch(void* const* d_in, const int* in_sizes, int n_in,
                              void* d_out, int out_size, void* d_ws, size_t ws_size,
                              hipStream_t stream) {
  const float* x  = (const float*)d_in[0];  // [4096,1024]
  const float* gw = (const float*)d_in[1];  // [1024,16]
  const float* gb = (const float*)d_in[2];  // [16]
  const float* pw = (const float*)d_in[3];  // [1024,1024,16]
  const float* pb = (const float*)d_in[4];  // [1024,16]
  float* out = (float*)d_out;               // [4096,1024]

  const size_t y_bytes = (size_t)BATCH * KP * sizeof(__hip_bfloat16);  // 135.3 MB
  const size_t w_bytes = (size_t)OUT_F * KP * sizeof(__hip_bfloat16);  //  33.8 MB
  const size_t g_bytes = (size_t)BATCH * NLEAF * sizeof(float);        //  0.26 MB

  if (ws_size >= y_bytes + w_bytes + g_bytes) {
    __hip_bfloat16* y = (__hip_bfloat16*)d_ws;
    __hip_bfloat16* W = (__hip_bfloat16*)((char*)d_ws + y_bytes);
    float*          g = (float*)((char*)d_ws + y_bytes + w_bytes);

    gate_kernel<<<BATCH / 4, 256, 0, stream>>>(x, gw, gb, g);
    pack_y_kernel<<<dim3((KP / 8 + 255) / 256, BATCH), 256, 0, stream>>>(x, g, y);
    pack_w_kernel<<<dim3((KP / 8 + 255) / 256, OUT_F), 256, 0, stream>>>(pw, pb, W);
    hipMemsetAsync(out, 0, (size_t)BATCH * OUT_F * sizeof(float), stream);
    gemm_kernel<<<dim3(BATCH / TM, OUT_F / TN, SPLITK), 256, 0, stream>>>(y, W, out);
  } else {
    float* g = (float*)d_ws;  // needs only 256 KB
    gate_kernel<<<BATCH / 4, 256, 0, stream>>>(x, gw, gb, g);
    fallback_kernel<<<BATCH, 256, 0, stream>>>(x, pw, pb, g, out);
  }
}

// Round 3
// 345.254 us; speedup vs baseline: 1.1839x; 1.1839x over previous
//
#include <hip/hip_runtime.h>
#include <hip/hip_bf16.h>
#include <stdint.h>

// Problem constants (from reference)
#define IN_F   1024
#define OUT_F  1024
#define NLEAF  16
#define BATCH  4096

// R3 reformulation:  leaf_out[b, n] = sum_i xb[b,i] * W'[n,i],  n = o*16+l.
// GEMM [4096 x 1024] x [1024 x 16384]: A is 8 MB (L2-resident), grid 32x128 =
// 4096 blocks (no split-K, no atomics), and the g-weighted l-reduction fuses
// into the epilogue (all 16 l's of an o sit in one 16-lane group).
#define KK      1024         // GEMM K = IN_F
#define NN      (OUT_F * NLEAF)
#define TM      128
#define TN      128
#define BK      32
#define KITERS  (KK / BK)    // 32

typedef __bf16 bf16x8 __attribute__((ext_vector_type(8)));
typedef float  f32x4  __attribute__((ext_vector_type(4)));

#define ASYNC_COPY16(gp, lp)                                                         \
  __builtin_amdgcn_global_load_lds((const __attribute__((address_space(1))) void*)(gp), \
                                   (__attribute__((address_space(3))) void*)(lp),       \
                                   16, 0, 0)

// ---------------------------------------------------------------------------
// Kernel 1: gating softmax.  g[b,l] = softmax_l(x[b,:] @ gw[:,l] + gb[l]).
// One wave per batch row; 4 waves (256 threads) per block.
// ---------------------------------------------------------------------------
__global__ __launch_bounds__(256) void gate_kernel(
    const float* __restrict__ x, const float* __restrict__ gw,
    const float* __restrict__ gb, float* __restrict__ g) {
  const int lane = threadIdx.x & 63;
  const int b = blockIdx.x * 4 + (threadIdx.x >> 6);

  float acc[NLEAF];
#pragma unroll
  for (int l = 0; l < NLEAF; ++l) acc[l] = 0.f;

  const float* xrow = x + b * IN_F;
#pragma unroll 4
  for (int tile = 0; tile < IN_F / 64; ++tile) {
    const int i = lane + tile * 64;
    const float xv = xrow[i];             // coalesced across lanes
    const float* gwp = gw + i * NLEAF;    // 64B row, L1/L2 resident (64 KB total)
#pragma unroll
    for (int l = 0; l < NLEAF; ++l) acc[l] += xv * gwp[l];
  }

  // butterfly reduce each of the 16 sums across the wave
#pragma unroll
  for (int l = 0; l < NLEAF; ++l) {
    float v = acc[l];
#pragma unroll
    for (int off = 32; off > 0; off >>= 1) v += __shfl_xor(v, off, 64);
    acc[l] = v;
  }

  // every lane now holds all 16 logits; softmax redundantly, lanes 0..15 write
  float mx = -1e30f;
#pragma unroll
  for (int l = 0; l < NLEAF; ++l) { acc[l] += gb[l]; mx = fmaxf(mx, acc[l]); }
  float s = 0.f;
  float e[NLEAF];
#pragma unroll
  for (int l = 0; l < NLEAF; ++l) { e[l] = __expf(acc[l] - mx); s += e[l]; }
  const float inv = 1.f / s;
  if (lane < NLEAF) g[b * NLEAF + lane] = e[lane] * inv;
}

// ---------------------------------------------------------------------------
// Kernel 2: pack x -> bf16.  8 elems (16 B out) per thread, fully coalesced.
// ---------------------------------------------------------------------------
__global__ __launch_bounds__(256) void pack_x_kernel(
    const float* __restrict__ x, __hip_bfloat16* __restrict__ xb) {
  const int idx = (blockIdx.x * 256 + threadIdx.x) * 8;
  const float4 v0 = *(const float4*)(x + idx);
  const float4 v1 = *(const float4*)(x + idx + 4);
  __align__(16) __hip_bfloat16 tmp[8];
  tmp[0] = __float2bfloat16(v0.x); tmp[1] = __float2bfloat16(v0.y);
  tmp[2] = __float2bfloat16(v0.z); tmp[3] = __float2bfloat16(v0.w);
  tmp[4] = __float2bfloat16(v1.x); tmp[5] = __float2bfloat16(v1.y);
  tmp[6] = __float2bfloat16(v1.z); tmp[7] = __float2bfloat16(v1.w);
  *(uint4*)(xb + idx) = *(const uint4*)tmp;
}

// ---------------------------------------------------------------------------
// Kernel 3: pack/transpose pw -> W'.  W'[o*16+l, i] = bf16(pw[o, i, l]).
// One block per o.  Reads are 4-B strided (stride 64 B) but every 64-B line
// (= one i, all 16 l) is fully consumed within the block via L1/L2 reuse;
// writes are coalesced 16-B.
// ---------------------------------------------------------------------------
__global__ __launch_bounds__(256) void pack_w_kernel(
    const float* __restrict__ pw, __hip_bfloat16* __restrict__ W) {
  const int o = blockIdx.x;
  const float* src = pw + (size_t)o * (IN_F * NLEAF);
#pragma unroll
  for (int j = 0; j < 8; ++j) {
    const int u = threadIdx.x + 256 * j;      // 0..2047 output uint4s
    const int l = u >> 7;                     // 0..15
    const int i0 = (u & 127) * 8;
    __align__(16) __hip_bfloat16 tmp[8];
#pragma unroll
    for (int jj = 0; jj < 8; ++jj)
      tmp[jj] = __float2bfloat16(src[(i0 + jj) * NLEAF + l]);
    *(uint4*)(W + ((size_t)o * NLEAF + l) * KK + i0) = *(const uint4*)tmp;
  }
}

// ---------------------------------------------------------------------------
// Kernel 4: bf16 MFMA GEMM with fused gated-reduction epilogue.
// 128x128 tile, BK=32, global_load_lds width=16, 4 waves x (4x4) 16x16x32
// MFMAs.  K-slot XOR swizzle from R2 (keeps SQ_LDS_BANK_CONFLICT = 0).
// Epilogue: n = o*16+l with l = lane&15  ->  butterfly-sum over the 16-lane
// group of (acc + pb[o,l]) * g[b,l] gives out[b,o] directly (sum_l g = 1).
// ---------------------------------------------------------------------------
__global__ __launch_bounds__(256, 2) void gemm_kernel(
    const __hip_bfloat16* __restrict__ Xb,  // [BATCH, KK]
    const __hip_bfloat16* __restrict__ W,   // [NN, KK], row n = o*16+l
    const float* __restrict__ g,            // [BATCH, NLEAF]
    const float* __restrict__ pb,           // [OUT_F, NLEAF]
    float* __restrict__ out) {              // [BATCH, OUT_F]
  __shared__ __align__(16) __hip_bfloat16 As[TM * BK];  // 8 KB
  __shared__ __align__(16) __hip_bfloat16 Bs[TN * BK];  // 8 KB

  const int t    = threadIdx.x;
  const int lane = t & 63;
  const int w    = t >> 6;
  const int quad = lane >> 4;
  const int r16  = lane & 15;

  const int m0 = blockIdx.x * TM;
  const int n0 = blockIdx.y * TN;

  const __hip_bfloat16* aG = Xb + (long)m0 * KK;
  const __hip_bfloat16* bG = W + (long)n0 * KK;

  // staging: 8 KB per tile = 512 16-byte chunks; chunk c -> row c>>2, LDS
  // 16B-slot c&3, GLOBAL 16B-slot (c&3)^((c>>3)&3)  (K-slot XOR swizzle).
  const int  c0 = t, c1 = t + 256;
  const int  sl0 = (c0 & 3) ^ ((c0 >> 3) & 3);
  const int  sl1 = (c1 & 3) ^ ((c1 >> 3) & 3);
  const long aOff0 = (long)(c0 >> 2) * KK + sl0 * 8;  // elements
  const long aOff1 = (long)(c1 >> 2) * KK + sl1 * 8;

  const int wm = (w >> 1) * 64;
  const int wn = (w & 1) * 64;
  const int swz = (r16 >> 1) & 3;   // read-side swizzle compensation

  f32x4 acc[4][4] = {};

  for (int it = 0; it < KITERS; ++it) {
    ASYNC_COPY16(aG + aOff0, (char*)As + c0 * 16);
    ASYNC_COPY16(aG + aOff1, (char*)As + c1 * 16);
    ASYNC_COPY16(bG + aOff0, (char*)Bs + c0 * 16);
    ASYNC_COPY16(bG + aOff1, (char*)Bs + c1 * 16);
    __syncthreads();

    bf16x8 af[4], bfr[4];
#pragma unroll
    for (int mi = 0; mi < 4; ++mi)
      af[mi] = *(const bf16x8*)(As + (wm + mi * 16 + r16) * BK + (quad ^ swz) * 8);
#pragma unroll
    for (int ni = 0; ni < 4; ++ni)
      bfr[ni] = *(const bf16x8*)(Bs + (wn + ni * 16 + r16) * BK + (quad ^ swz) * 8);

#pragma unroll
    for (int mi = 0; mi < 4; ++mi)
#pragma unroll
      for (int ni = 0; ni < 4; ++ni)
        acc[mi][ni] = __builtin_amdgcn_mfma_f32_16x16x32_bf16(
            af[mi], bfr[ni], acc[mi][ni], 0, 0, 0);

    __syncthreads();
    aG += BK;
    bG += BK;
  }

  // Fused epilogue.  C/D layout: col = lane&15 (= l), row = quad*4 + reg.
#pragma unroll
  for (int ni = 0; ni < 4; ++ni) {
    const int o = (n0 >> 4) + (wn >> 4) + ni;      // global o for this frag col
    const float pbv = pb[o * NLEAF + r16];         // pb[o, l],  l = r16
#pragma unroll
    for (int mi = 0; mi < 4; ++mi) {
#pragma unroll
      for (int r = 0; r < 4; ++r) {
        const int row = m0 + wm + mi * 16 + quad * 4 + r;
        float v = (acc[mi][ni][r] + pbv) * g[row * NLEAF + r16];
        v += __shfl_xor(v, 1);
        v += __shfl_xor(v, 2);
        v += __shfl_xor(v, 4);
        v += __shfl_xor(v, 8);                     // sum over l within 16-group
        if (r16 == 0) out[(long)row * OUT_F + o] = v;
      }
    }
  }
}

// ---------------------------------------------------------------------------
// Fallback (ws too small for packed buffers): slow but correct fp32 path.
// ---------------------------------------------------------------------------
__global__ __launch_bounds__(256) void fallback_kernel(
    const float* __restrict__ x, const float* __restrict__ pw,
    const float* __restrict__ pb, const float* __restrict__ g,
    float* __restrict__ out) {
  const int b = blockIdx.x;
  __shared__ float xs[IN_F];
  __shared__ float gs[NLEAF];
  const int t = threadIdx.x;
  for (int j = t; j < IN_F; j += 256) xs[j] = x[(long)b * IN_F + j];
  if (t < NLEAF) gs[t] = g[b * NLEAF + t];
  __syncthreads();
  for (int o = t; o < OUT_F; o += 256) {
    const float* pwo = pw + (long)o * (IN_F * NLEAF);
    float acc = 0.f;
    for (int i = 0; i < IN_F; ++i) {
      const float xv = xs[i];
      float wsum = 0.f;
#pragma unroll
      for (int l = 0; l < NLEAF; ++l) wsum += gs[l] * pwo[i * NLEAF + l];
      acc += xv * wsum;
    }
    float bias = 0.f;
#pragma unroll
    for (int l = 0; l < NLEAF; ++l) bias += gs[l] * pb[o * NLEAF + l];
    out[(long)b * OUT_F + o] = acc + bias;
  }
}

extern "C" void kernel_launch(void* const* d_in, const int* in_sizes, int n_in,
                              void* d_out, int out_size, void* d_ws, size_t ws_size,
                              hipStream_t stream) {
  const float* x  = (const float*)d_in[0];  // [4096,1024]
  const float* gw = (const float*)d_in[1];  // [1024,16]
  const float* gb = (const float*)d_in[2];  // [16]
  const float* pw = (const float*)d_in[3];  // [1024,1024,16]
  const float* pb = (const float*)d_in[4];  // [1024,16]
  float* out = (float*)d_out;               // [4096,1024]

  const size_t w_bytes  = (size_t)NN * KK * sizeof(__hip_bfloat16);    // 33.6 MB
  const size_t xb_bytes = (size_t)BATCH * KK * sizeof(__hip_bfloat16); //  8.4 MB
  const size_t g_bytes  = (size_t)BATCH * NLEAF * sizeof(float);       //  0.26 MB

  if (ws_size >= w_bytes + xb_bytes + g_bytes) {
    __hip_bfloat16* W  = (__hip_bfloat16*)d_ws;
    __hip_bfloat16* xb = (__hip_bfloat16*)((char*)d_ws + w_bytes);
    float*          g  = (float*)((char*)d_ws + w_bytes + xb_bytes);

    gate_kernel<<<BATCH / 4, 256, 0, stream>>>(x, gw, gb, g);
    pack_x_kernel<<<(BATCH * IN_F / 8) / 256, 256, 0, stream>>>(x, xb);
    pack_w_kernel<<<OUT_F, 256, 0, stream>>>(pw, W);
    gemm_kernel<<<dim3(BATCH / TM, NN / TN), 256, 0, stream>>>(xb, W, g, pb, out);
  } else {
    float* g = (float*)d_ws;  // needs only 256 KB
    gate_kernel<<<BATCH / 4, 256, 0, stream>>>(x, gw, gb, g);
    fallback_kernel<<<BATCH, 256, 0, stream>>>(x, pw, pb, g, out);
  }
}

// Round 4
// 286.188 us; speedup vs baseline: 1.4282x; 1.2064x over previous
//
#include <hip/hip_runtime.h>
#include <hip/hip_bf16.h>
#include <stdint.h>

// Problem constants (from reference)
#define IN_F   1024
#define OUT_F  1024
#define NLEAF  16
#define BATCH  4096

// R4: GEMM C'[n, b] = sum_i W'[n,i] * Xb[b,i],  n = o*16+l  (operands SWAPPED
// vs R3 so n is the C-tile ROW dim).  Each 16x16 frag then covers exactly one
// o with l = quad*4+reg -> the g-weighted l-reduction is 3 register adds + 2
// shuffles, and the 4 mi-frags are 4 consecutive o's -> one float4 store.
#define KK      1024         // GEMM K = IN_F
#define NN      (OUT_F * NLEAF)
#define TM      128          // n-tile
#define TN      128          // b-tile
#define BK      32
#define KITERS  (KK / BK)    // 32
#define GS_PAD  138          // g-tile LDS row stride (<=2-way conflicts)

typedef __bf16 bf16x8 __attribute__((ext_vector_type(8)));
typedef float  f32x4  __attribute__((ext_vector_type(4)));

#define ASYNC_COPY16(gp, lp)                                                         \
  __builtin_amdgcn_global_load_lds((const __attribute__((address_space(1))) void*)(gp), \
                                   (__attribute__((address_space(3))) void*)(lp),       \
                                   16, 0, 0)

// ---------------------------------------------------------------------------
// Kernel 1: fused gating softmax + x->bf16 pack.  Block = 4 batch rows
// (one wave each).  Lane remap (i4 = lane>>4, l = lane&15) makes the gw reads
// gw[k*64 + lane] -- perfectly coalesced (vs 64-B-strided scalar in R3).
// ---------------------------------------------------------------------------
__global__ __launch_bounds__(256) void gate_pack_kernel(
    const float* __restrict__ x, const float* __restrict__ gw,
    const float* __restrict__ gb, float* __restrict__ g,
    __hip_bfloat16* __restrict__ xb) {
  const int lane = threadIdx.x & 63;
  const int wv   = threadIdx.x >> 6;
  const int b    = blockIdx.x * 4 + wv;
  const int i4   = lane >> 4;
  const int l    = lane & 15;

  const float* xrow = x + (size_t)b * IN_F;
  float acc = 0.f;
#pragma unroll 8
  for (int k = 0; k < IN_F / 4; ++k) {
    const float xv = xrow[k * 4 + i4];          // same addr per 16-group (L1)
    const float wvv = gw[k * 64 + lane];        // coalesced
    acc = fmaf(xv, wvv, acc);
  }
  // sum partials over i4 (lanes differing in bits 4..5)
  acc += __shfl_xor(acc, 16);
  acc += __shfl_xor(acc, 32);
  float logit = acc + gb[l];
  // softmax over l within each 16-lane group
  float m = logit;
#pragma unroll
  for (int off = 8; off > 0; off >>= 1) m = fmaxf(m, __shfl_xor(m, off));
  float e = __expf(logit - m);
  float s = e;
#pragma unroll
  for (int off = 8; off > 0; off >>= 1) s += __shfl_xor(s, off);
  if (lane < NLEAF) g[b * NLEAF + l] = e / s;

  // pack this block's 4 rows of x -> bf16 (x hot in L1/L2)
  const float* xblk = x + (size_t)blockIdx.x * 4 * IN_F;
  __hip_bfloat16* xbblk = xb + (size_t)blockIdx.x * 4 * IN_F;
#pragma unroll
  for (int j = 0; j < 2; ++j) {
    const int f = (threadIdx.x + 256 * j) * 8;
    const float4 a0 = *(const float4*)(xblk + f);
    const float4 a1 = *(const float4*)(xblk + f + 4);
    __align__(16) __hip_bfloat16 tmp[8];
    tmp[0] = __float2bfloat16(a0.x); tmp[1] = __float2bfloat16(a0.y);
    tmp[2] = __float2bfloat16(a0.z); tmp[3] = __float2bfloat16(a0.w);
    tmp[4] = __float2bfloat16(a1.x); tmp[5] = __float2bfloat16(a1.y);
    tmp[6] = __float2bfloat16(a1.z); tmp[7] = __float2bfloat16(a1.w);
    *(uint4*)(xbblk + f) = *(const uint4*)tmp;
  }
}

// ---------------------------------------------------------------------------
// Kernel 2: pack/transpose pw -> W' via LDS.  W'[o*16+l, i] = bf16(pw[o,i,l]).
// Block per o; 4 chunks of 256 i.  Loads: thread t owns i=t (4 float4, lines
// fully consumed via L1).  Transposed ds_write_b16 (2-way max).  Readout:
// b128 LDS reads + coalesced 16-B global stores.
// ---------------------------------------------------------------------------
__global__ __launch_bounds__(256) void pack_w_kernel(
    const float* __restrict__ pw, __hip_bfloat16* __restrict__ W) {
  __shared__ __align__(16) __hip_bfloat16 lt[16 * 264];  // 264 = 256 i + pad
  const int o = blockIdx.x;
  const int t = threadIdx.x;
  const float* src = pw + (size_t)o * (IN_F * NLEAF);

  for (int ch = 0; ch < 4; ++ch) {
    const float4* p = (const float4*)(src + ch * 4096 + t * 16);  // i=t, 16 l
    const float4 v0 = p[0], v1 = p[1], v2 = p[2], v3 = p[3];
    if (ch) __syncthreads();   // prev readout done before overwriting lt
    lt[ 0 * 264 + t] = __float2bfloat16(v0.x);
    lt[ 1 * 264 + t] = __float2bfloat16(v0.y);
    lt[ 2 * 264 + t] = __float2bfloat16(v0.z);
    lt[ 3 * 264 + t] = __float2bfloat16(v0.w);
    lt[ 4 * 264 + t] = __float2bfloat16(v1.x);
    lt[ 5 * 264 + t] = __float2bfloat16(v1.y);
    lt[ 6 * 264 + t] = __float2bfloat16(v1.z);
    lt[ 7 * 264 + t] = __float2bfloat16(v1.w);
    lt[ 8 * 264 + t] = __float2bfloat16(v2.x);
    lt[ 9 * 264 + t] = __float2bfloat16(v2.y);
    lt[10 * 264 + t] = __float2bfloat16(v2.z);
    lt[11 * 264 + t] = __float2bfloat16(v2.w);
    lt[12 * 264 + t] = __float2bfloat16(v3.x);
    lt[13 * 264 + t] = __float2bfloat16(v3.y);
    lt[14 * 264 + t] = __float2bfloat16(v3.z);
    lt[15 * 264 + t] = __float2bfloat16(v3.w);
    __syncthreads();
#pragma unroll
    for (int jj = 0; jj < 2; ++jj) {
      const int u = t + 256 * jj;        // 512 uint4 per chunk
      const int l = u >> 5;
      const int i8 = (u & 31) * 8;
      *(uint4*)(W + ((size_t)o * NLEAF + l) * KK + ch * 256 + i8) =
          *(const uint4*)(lt + l * 264 + i8);
    }
  }
}

// ---------------------------------------------------------------------------
// Kernel 3: bf16 MFMA GEMM, operands swapped (A = W', B = Xb), fused epilogue.
// 128x128 tile, BK=32, global_load_lds width=16, K-slot XOR swizzle (R2).
// acc[mi][ni][r] = C'[n = n0+wn+mi*16+quad*4+r][b = b0+wb+ni*16+r16];
// l = quad*4+r, o = (n0+wn)/16 + mi (4 consecutive o's per wave).
// Epilogue: v = sum_r (acc+pb[o,l])*g[b,l]; butterfly over quads; one float4
// store per ni by quad-0 lanes.  No atomics, no memset.
// ---------------------------------------------------------------------------
__global__ __launch_bounds__(256, 2) void gemm_kernel(
    const __hip_bfloat16* __restrict__ Xb,  // [BATCH, KK]
    const __hip_bfloat16* __restrict__ W,   // [NN, KK], row n = o*16+l
    const float* __restrict__ g,            // [BATCH, NLEAF]
    const float* __restrict__ pb,           // [OUT_F, NLEAF]
    float* __restrict__ out) {              // [BATCH, OUT_F]
  __shared__ __align__(16) __hip_bfloat16 As[TM * BK];  // W' tile, 8 KB
  __shared__ __align__(16) __hip_bfloat16 Bs[TN * BK];  // Xb tile, 8 KB
  __shared__ float gs[NLEAF * GS_PAD];                  // g[l][b_local], 8.8 KB
  __shared__ float pbs[8 * NLEAF];                      // pb[o_local][l], 512 B

  const int t    = threadIdx.x;
  const int lane = t & 63;
  const int w    = t >> 6;
  const int quad = lane >> 4;
  const int r16  = lane & 15;

  const int b0 = blockIdx.x * TN;
  const int n0 = blockIdx.y * TM;

  const __hip_bfloat16* aG = W + (long)n0 * KK;   // A operand = W'
  const __hip_bfloat16* bG = Xb + (long)b0 * KK;  // B operand = Xb

  // stage g-tile (transposed, padded) and pb-tile; covered by first barrier
#pragma unroll
  for (int j = 0; j < 8; ++j) {
    const int f = t + 256 * j;           // 0..2047
    gs[(f & 15) * GS_PAD + (f >> 4)] = g[b0 * NLEAF + f];
  }
  if (t < 128) pbs[t] = pb[n0 + t];      // n0 = o0*16; pb flat [o,l]

  // staging: 512 16-B chunks/tile; chunk c -> row c>>2, LDS slot c&3,
  // GLOBAL slot (c&3)^((c>>3)&3)  (K-slot XOR swizzle, keeps conflicts = 0)
  const int  c0 = t, c1 = t + 256;
  const int  sl0 = (c0 & 3) ^ ((c0 >> 3) & 3);
  const int  sl1 = (c1 & 3) ^ ((c1 >> 3) & 3);
  const long aOff0 = (long)(c0 >> 2) * KK + sl0 * 8;
  const long aOff1 = (long)(c1 >> 2) * KK + sl1 * 8;

  const int wn = (w >> 1) * 64;   // n-dir within tile
  const int wb = (w & 1) * 64;    // b-dir within tile
  const int swz = (r16 >> 1) & 3;

  f32x4 acc[4][4] = {};

  for (int it = 0; it < KITERS; ++it) {
    ASYNC_COPY16(aG + aOff0, (char*)As + c0 * 16);
    ASYNC_COPY16(aG + aOff1, (char*)As + c1 * 16);
    ASYNC_COPY16(bG + aOff0, (char*)Bs + c0 * 16);
    ASYNC_COPY16(bG + aOff1, (char*)Bs + c1 * 16);
    __syncthreads();

    bf16x8 af[4], bfr[4];
#pragma unroll
    for (int mi = 0; mi < 4; ++mi)
      af[mi] = *(const bf16x8*)(As + (wn + mi * 16 + r16) * BK + (quad ^ swz) * 8);
#pragma unroll
    for (int ni = 0; ni < 4; ++ni)
      bfr[ni] = *(const bf16x8*)(Bs + (wb + ni * 16 + r16) * BK + (quad ^ swz) * 8);

#pragma unroll
    for (int mi = 0; mi < 4; ++mi)
#pragma unroll
      for (int ni = 0; ni < 4; ++ni)
        acc[mi][ni] = __builtin_amdgcn_mfma_f32_16x16x32_bf16(
            af[mi], bfr[ni], acc[mi][ni], 0, 0, 0);

    __syncthreads();
    aG += BK;
    bG += BK;
  }

  // ---- fused epilogue ----
  float pbv[4][4];                        // [mi][r]: pb[o_local = wn/16+mi, l]
#pragma unroll
  for (int mi = 0; mi < 4; ++mi)
#pragma unroll
    for (int r = 0; r < 4; ++r)
      pbv[mi][r] = pbs[((wn >> 4) + mi) * NLEAF + quad * 4 + r];  // broadcast

  const int oBase = (n0 >> 4) + (wn >> 4);   // 4 consecutive o's (mi)
#pragma unroll
  for (int ni = 0; ni < 4; ++ni) {
    const int bl = wb + ni * 16 + r16;
    float gv[4];
#pragma unroll
    for (int r = 0; r < 4; ++r) gv[r] = gs[(quad * 4 + r) * GS_PAD + bl];
    float rv[4];
#pragma unroll
    for (int mi = 0; mi < 4; ++mi) {
      float v = 0.f;
#pragma unroll
      for (int r = 0; r < 4; ++r)
        v = fmaf(acc[mi][ni][r] + pbv[mi][r], gv[r], v);
      v += __shfl_xor(v, 16);
      v += __shfl_xor(v, 32);              // sum over quads -> full sum_l
      rv[mi] = v;
    }
    if (quad == 0)
      *(float4*)(out + (long)(b0 + bl) * OUT_F + oBase) =
          make_float4(rv[0], rv[1], rv[2], rv[3]);
  }
}

// ---------------------------------------------------------------------------
// Fallback (ws too small for packed buffers): slow but correct fp32 path.
// ---------------------------------------------------------------------------
__global__ __launch_bounds__(256) void gate_kernel_fb(
    const float* __restrict__ x, const float* __restrict__ gw,
    const float* __restrict__ gb, float* __restrict__ g) {
  const int lane = threadIdx.x & 63;
  const int wv   = threadIdx.x >> 6;
  const int b    = blockIdx.x * 4 + wv;
  const int i4   = lane >> 4;
  const int l    = lane & 15;
  const float* xrow = x + (size_t)b * IN_F;
  float acc = 0.f;
  for (int k = 0; k < IN_F / 4; ++k)
    acc = fmaf(xrow[k * 4 + i4], gw[k * 64 + lane], acc);
  acc += __shfl_xor(acc, 16);
  acc += __shfl_xor(acc, 32);
  float logit = acc + gb[l];
  float m = logit;
  for (int off = 8; off > 0; off >>= 1) m = fmaxf(m, __shfl_xor(m, off));
  float e = __expf(logit - m);
  float s = e;
  for (int off = 8; off > 0; off >>= 1) s += __shfl_xor(s, off);
  if (lane < NLEAF) g[b * NLEAF + l] = e / s;
}

__global__ __launch_bounds__(256) void fallback_kernel(
    const float* __restrict__ x, const float* __restrict__ pw,
    const float* __restrict__ pb, const float* __restrict__ g,
    float* __restrict__ out) {
  const int b = blockIdx.x;
  __shared__ float xs[IN_F];
  __shared__ float gsl[NLEAF];
  const int t = threadIdx.x;
  for (int j = t; j < IN_F; j += 256) xs[j] = x[(long)b * IN_F + j];
  if (t < NLEAF) gsl[t] = g[b * NLEAF + t];
  __syncthreads();
  for (int o = t; o < OUT_F; o += 256) {
    const float* pwo = pw + (long)o * (IN_F * NLEAF);
    float acc = 0.f;
    for (int i = 0; i < IN_F; ++i) {
      const float xv = xs[i];
      float wsum = 0.f;
#pragma unroll
      for (int l = 0; l < NLEAF; ++l) wsum += gsl[l] * pwo[i * NLEAF + l];
      acc += xv * wsum;
    }
    float bias = 0.f;
#pragma unroll
    for (int l = 0; l < NLEAF; ++l) bias += gsl[l] * pb[o * NLEAF + l];
    out[(long)b * OUT_F + o] = acc + bias;
  }
}

extern "C" void kernel_launch(void* const* d_in, const int* in_sizes, int n_in,
                              void* d_out, int out_size, void* d_ws, size_t ws_size,
                              hipStream_t stream) {
  const float* x  = (const float*)d_in[0];  // [4096,1024]
  const float* gw = (const float*)d_in[1];  // [1024,16]
  const float* gb = (const float*)d_in[2];  // [16]
  const float* pw = (const float*)d_in[3];  // [1024,1024,16]
  const float* pb = (const float*)d_in[4];  // [1024,16]
  float* out = (float*)d_out;               // [4096,1024]

  const size_t w_bytes  = (size_t)NN * KK * sizeof(__hip_bfloat16);    // 33.6 MB
  const size_t xb_bytes = (size_t)BATCH * KK * sizeof(__hip_bfloat16); //  8.4 MB
  const size_t g_bytes  = (size_t)BATCH * NLEAF * sizeof(float);       //  0.26 MB

  if (ws_size >= w_bytes + xb_bytes + g_bytes) {
    __hip_bfloat16* W  = (__hip_bfloat16*)d_ws;
    __hip_bfloat16* xb = (__hip_bfloat16*)((char*)d_ws + w_bytes);
    float*          g  = (float*)((char*)d_ws + w_bytes + xb_bytes);

    gate_pack_kernel<<<BATCH / 4, 256, 0, stream>>>(x, gw, gb, g, xb);
    pack_w_kernel<<<OUT_F, 256, 0, stream>>>(pw, W);
    gemm_kernel<<<dim3(BATCH / TN, NN / TM), 256, 0, stream>>>(xb, W, g, pb, out);
  } else {
    float* g = (float*)d_ws;  // needs only 256 KB
    gate_kernel_fb<<<BATCH / 4, 256, 0, stream>>>(x, gw, gb, g);
    fallback_kernel<<<BATCH, 256, 0, stream>>>(x, pw, pb, g, out);
  }
}

// Round 5
// 283.500 us; speedup vs baseline: 1.4418x; 1.0095x over previous
//
#include <hip/hip_runtime.h>
#include <hip/hip_bf16.h>
#include <stdint.h>

// Problem constants (from reference)
#define IN_F   1024
#define OUT_F  1024
#define NLEAF  16
#define BATCH  4096

// GEMM C'[n, b] = sum_i W'[n,i] * Xb[b,i],  n = o*16+l  (n = C-tile ROW dim).
// Each 16x16 frag covers one o with l = quad*4+reg -> the g-weighted
// l-reduction is 3 register fmas + 2 shuffles; 4 mi-frags = 4 consecutive
// o's -> one float4 store.  R5: g/pb tiles alias the As/Bs LDS (epilogue-
// only) -> static LDS 16 KB; __launch_bounds__(256,4) -> 4 waves/SIMD.
#define KK      1024         // GEMM K = IN_F
#define NN      (OUT_F * NLEAF)
#define TM      128          // n-tile
#define TN      128          // b-tile
#define BK      32
#define KITERS  (KK / BK)    // 32
#define GS_PAD  138          // g-tile LDS row stride (<=2-way conflicts)

typedef __bf16 bf16x8 __attribute__((ext_vector_type(8)));
typedef float  f32x4  __attribute__((ext_vector_type(4)));

#define ASYNC_COPY16(gp, lp)                                                         \
  __builtin_amdgcn_global_load_lds((const __attribute__((address_space(1))) void*)(gp), \
                                   (__attribute__((address_space(3))) void*)(lp),       \
                                   16, 0, 0)

// ---------------------------------------------------------------------------
// Kernel 1: fused prep.  Blocks [0,1024): transpose/pack pw -> W'.
// Blocks [1024,2048): gating softmax + x->bf16 pack (4 batch rows/block).
// Independent work fused into one dispatch so the cheap gate path hides
// under the pack_w path instead of serializing in-stream.
// ---------------------------------------------------------------------------
__global__ __launch_bounds__(256) void prep_kernel(
    const float* __restrict__ x, const float* __restrict__ gw,
    const float* __restrict__ gb, const float* __restrict__ pw,
    float* __restrict__ g, __hip_bfloat16* __restrict__ xb,
    __hip_bfloat16* __restrict__ W) {
  __shared__ __align__(16) __hip_bfloat16 lt[16 * 264];
  const int t = threadIdx.x;

  if (blockIdx.x < OUT_F) {
    // ---- pack_w path: W'[o*16+l, i] = bf16(pw[o,i,l]) via LDS transpose ----
    const int o = blockIdx.x;
    const float* src = pw + (size_t)o * (IN_F * NLEAF);
    for (int ch = 0; ch < 4; ++ch) {
      const float4* p = (const float4*)(src + ch * 4096 + t * 16);  // i=t, 16 l
      const float4 v0 = p[0], v1 = p[1], v2 = p[2], v3 = p[3];
      if (ch) __syncthreads();   // prev readout done before overwriting lt
      lt[ 0 * 264 + t] = __float2bfloat16(v0.x);
      lt[ 1 * 264 + t] = __float2bfloat16(v0.y);
      lt[ 2 * 264 + t] = __float2bfloat16(v0.z);
      lt[ 3 * 264 + t] = __float2bfloat16(v0.w);
      lt[ 4 * 264 + t] = __float2bfloat16(v1.x);
      lt[ 5 * 264 + t] = __float2bfloat16(v1.y);
      lt[ 6 * 264 + t] = __float2bfloat16(v1.z);
      lt[ 7 * 264 + t] = __float2bfloat16(v1.w);
      lt[ 8 * 264 + t] = __float2bfloat16(v2.x);
      lt[ 9 * 264 + t] = __float2bfloat16(v2.y);
      lt[10 * 264 + t] = __float2bfloat16(v2.z);
      lt[11 * 264 + t] = __float2bfloat16(v2.w);
      lt[12 * 264 + t] = __float2bfloat16(v3.x);
      lt[13 * 264 + t] = __float2bfloat16(v3.y);
      lt[14 * 264 + t] = __float2bfloat16(v3.z);
      lt[15 * 264 + t] = __float2bfloat16(v3.w);
      __syncthreads();
#pragma unroll
      for (int jj = 0; jj < 2; ++jj) {
        const int u = t + 256 * jj;        // 512 uint4 per chunk
        const int l = u >> 5;
        const int i8 = (u & 31) * 8;
        *(uint4*)(W + ((size_t)o * NLEAF + l) * KK + ch * 256 + i8) =
            *(const uint4*)(lt + l * 264 + i8);
      }
    }
  } else {
    // ---- gate + pack_x path ----
    const int blk  = blockIdx.x - OUT_F;
    const int lane = t & 63;
    const int wv   = t >> 6;
    const int b    = blk * 4 + wv;
    const int i4   = lane >> 4;
    const int l    = lane & 15;

    const float* xrow = x + (size_t)b * IN_F;
    float acc = 0.f;
#pragma unroll 8
    for (int k = 0; k < IN_F / 4; ++k) {
      const float xv = xrow[k * 4 + i4];          // same addr per 16-group (L1)
      const float wvv = gw[k * 64 + lane];        // coalesced
      acc = fmaf(xv, wvv, acc);
    }
    acc += __shfl_xor(acc, 16);
    acc += __shfl_xor(acc, 32);
    float logit = acc + gb[l];
    float m = logit;
#pragma unroll
    for (int off = 8; off > 0; off >>= 1) m = fmaxf(m, __shfl_xor(m, off));
    float e = __expf(logit - m);
    float s = e;
#pragma unroll
    for (int off = 8; off > 0; off >>= 1) s += __shfl_xor(s, off);
    if (lane < NLEAF) g[b * NLEAF + l] = e / s;

    const float* xblk = x + (size_t)blk * 4 * IN_F;
    __hip_bfloat16* xbblk = xb + (size_t)blk * 4 * IN_F;
#pragma unroll
    for (int j = 0; j < 2; ++j) {
      const int f = (t + 256 * j) * 8;
      const float4 a0 = *(const float4*)(xblk + f);
      const float4 a1 = *(const float4*)(xblk + f + 4);
      __align__(16) __hip_bfloat16 tmp[8];
      tmp[0] = __float2bfloat16(a0.x); tmp[1] = __float2bfloat16(a0.y);
      tmp[2] = __float2bfloat16(a0.z); tmp[3] = __float2bfloat16(a0.w);
      tmp[4] = __float2bfloat16(a1.x); tmp[5] = __float2bfloat16(a1.y);
      tmp[6] = __float2bfloat16(a1.z); tmp[7] = __float2bfloat16(a1.w);
      *(uint4*)(xbblk + f) = *(const uint4*)tmp;
    }
  }
}

// ---------------------------------------------------------------------------
// Kernel 2: bf16 MFMA GEMM, A = W', B = Xb, fused gated-reduction epilogue.
// 128x128 tile, BK=32, global_load_lds width=16, K-slot XOR swizzle.
// acc[mi][ni][r] = C'[n = n0+wn+mi*16+quad*4+r][b = b0+wb+ni*16+r16];
// l = quad*4+r, o = (n0+wn)/16 + mi.  g/pb tiles are staged into the SAME
// LDS as As/Bs after the K-loop (epilogue-only use) -> 16 KB static LDS.
// ---------------------------------------------------------------------------
__global__ __launch_bounds__(256, 4) void gemm_kernel(
    const __hip_bfloat16* __restrict__ Xb,  // [BATCH, KK]
    const __hip_bfloat16* __restrict__ W,   // [NN, KK], row n = o*16+l
    const float* __restrict__ g,            // [BATCH, NLEAF]
    const float* __restrict__ pb,           // [OUT_F, NLEAF]
    float* __restrict__ out) {              // [BATCH, OUT_F]
  __shared__ __align__(16) char smem[16384];
  __hip_bfloat16* As = (__hip_bfloat16*)smem;           // [TM*BK], 8 KB
  __hip_bfloat16* Bs = (__hip_bfloat16*)(smem + 8192);  // [TN*BK], 8 KB
  float* gs  = (float*)smem;           // epilogue alias: [16][GS_PAD] = 8832 B
  float* pbs = (float*)(smem + 8832);  // epilogue alias: [128] = 512 B

  const int t    = threadIdx.x;
  const int lane = t & 63;
  const int w    = t >> 6;
  const int quad = lane >> 4;
  const int r16  = lane & 15;

  const int b0 = blockIdx.x * TN;
  const int n0 = blockIdx.y * TM;

  const __hip_bfloat16* aG = W + (long)n0 * KK;   // A operand = W'
  const __hip_bfloat16* bG = Xb + (long)b0 * KK;  // B operand = Xb

  // staging: 512 16-B chunks/tile; chunk c -> row c>>2, LDS slot c&3,
  // GLOBAL slot (c&3)^((c>>3)&3)  (K-slot XOR swizzle, keeps conflicts ~0)
  const int  c0 = t, c1 = t + 256;
  const int  sl0 = (c0 & 3) ^ ((c0 >> 3) & 3);
  const int  sl1 = (c1 & 3) ^ ((c1 >> 3) & 3);
  const long aOff0 = (long)(c0 >> 2) * KK + sl0 * 8;
  const long aOff1 = (long)(c1 >> 2) * KK + sl1 * 8;

  const int wn = (w >> 1) * 64;   // n-dir within tile
  const int wb = (w & 1) * 64;    // b-dir within tile
  const int swz = (r16 >> 1) & 3;

  f32x4 acc[4][4] = {};

  for (int it = 0; it < KITERS; ++it) {
    ASYNC_COPY16(aG + aOff0, (char*)As + c0 * 16);
    ASYNC_COPY16(aG + aOff1, (char*)As + c1 * 16);
    ASYNC_COPY16(bG + aOff0, (char*)Bs + c0 * 16);
    ASYNC_COPY16(bG + aOff1, (char*)Bs + c1 * 16);
    __syncthreads();

    bf16x8 af[4], bfr[4];
#pragma unroll
    for (int mi = 0; mi < 4; ++mi)
      af[mi] = *(const bf16x8*)(As + (wn + mi * 16 + r16) * BK + (quad ^ swz) * 8);
#pragma unroll
    for (int ni = 0; ni < 4; ++ni)
      bfr[ni] = *(const bf16x8*)(Bs + (wb + ni * 16 + r16) * BK + (quad ^ swz) * 8);

#pragma unroll
    for (int mi = 0; mi < 4; ++mi)
#pragma unroll
      for (int ni = 0; ni < 4; ++ni)
        acc[mi][ni] = __builtin_amdgcn_mfma_f32_16x16x32_bf16(
            af[mi], bfr[ni], acc[mi][ni], 0, 0, 0);

    __syncthreads();   // also guarantees As/Bs dead before epilogue aliasing
    aG += BK;
    bG += BK;
  }

  // ---- stage g (transposed, padded) and pb into the aliased LDS ----
#pragma unroll
  for (int j = 0; j < 8; ++j) {
    const int f = t + 256 * j;           // 0..2047
    gs[(f & 15) * GS_PAD + (f >> 4)] = g[b0 * NLEAF + f];
  }
  if (t < 128) pbs[t] = pb[n0 + t];      // n0 = o0*16; pb flat [o,l]
  __syncthreads();

  // ---- fused epilogue ----
  float pbv[4][4];                        // [mi][r]: pb[o_local = wn/16+mi, l]
#pragma unroll
  for (int mi = 0; mi < 4; ++mi)
#pragma unroll
    for (int r = 0; r < 4; ++r)
      pbv[mi][r] = pbs[((wn >> 4) + mi) * NLEAF + quad * 4 + r];  // broadcast

  const int oBase = (n0 >> 4) + (wn >> 4);   // 4 consecutive o's (mi)
#pragma unroll
  for (int ni = 0; ni < 4; ++ni) {
    const int bl = wb + ni * 16 + r16;
    float gv[4];
#pragma unroll
    for (int r = 0; r < 4; ++r) gv[r] = gs[(quad * 4 + r) * GS_PAD + bl];
    float rv[4];
#pragma unroll
    for (int mi = 0; mi < 4; ++mi) {
      float v = 0.f;
#pragma unroll
      for (int r = 0; r < 4; ++r)
        v = fmaf(acc[mi][ni][r] + pbv[mi][r], gv[r], v);
      v += __shfl_xor(v, 16);
      v += __shfl_xor(v, 32);              // sum over quads -> full sum_l
      rv[mi] = v;
    }
    if (quad == 0)
      *(float4*)(out + (long)(b0 + bl) * OUT_F + oBase) =
          make_float4(rv[0], rv[1], rv[2], rv[3]);
  }
}

// ---------------------------------------------------------------------------
// Fallback (ws too small for packed buffers): slow but correct fp32 path.
// ---------------------------------------------------------------------------
__global__ __launch_bounds__(256) void gate_kernel_fb(
    const float* __restrict__ x, const float* __restrict__ gw,
    const float* __restrict__ gb, float* __restrict__ g) {
  const int lane = threadIdx.x & 63;
  const int wv   = threadIdx.x >> 6;
  const int b    = blockIdx.x * 4 + wv;
  const int i4   = lane >> 4;
  const int l    = lane & 15;
  const float* xrow = x + (size_t)b * IN_F;
  float acc = 0.f;
  for (int k = 0; k < IN_F / 4; ++k)
    acc = fmaf(xrow[k * 4 + i4], gw[k * 64 + lane], acc);
  acc += __shfl_xor(acc, 16);
  acc += __shfl_xor(acc, 32);
  float logit = acc + gb[l];
  float m = logit;
  for (int off = 8; off > 0; off >>= 1) m = fmaxf(m, __shfl_xor(m, off));
  float e = __expf(logit - m);
  float s = e;
  for (int off = 8; off > 0; off >>= 1) s += __shfl_xor(s, off);
  if (lane < NLEAF) g[b * NLEAF + l] = e / s;
}

__global__ __launch_bounds__(256) void fallback_kernel(
    const float* __restrict__ x, const float* __restrict__ pw,
    const float* __restrict__ pb, const float* __restrict__ g,
    float* __restrict__ out) {
  const int b = blockIdx.x;
  __shared__ float xs[IN_F];
  __shared__ float gsl[NLEAF];
  const int t = threadIdx.x;
  for (int j = t; j < IN_F; j += 256) xs[j] = x[(long)b * IN_F + j];
  if (t < NLEAF) gsl[t] = g[b * NLEAF + t];
  __syncthreads();
  for (int o = t; o < OUT_F; o += 256) {
    const float* pwo = pw + (long)o * (IN_F * NLEAF);
    float acc = 0.f;
    for (int i = 0; i < IN_F; ++i) {
      const float xv = xs[i];
      float wsum = 0.f;
#pragma unroll
      for (int l = 0; l < NLEAF; ++l) wsum += gsl[l] * pwo[i * NLEAF + l];
      acc += xv * wsum;
    }
    float bias = 0.f;
#pragma unroll
    for (int l = 0; l < NLEAF; ++l) bias += gsl[l] * pb[o * NLEAF + l];
    out[(long)b * OUT_F + o] = acc + bias;
  }
}

extern "C" void kernel_launch(void* const* d_in, const int* in_sizes, int n_in,
                              void* d_out, int out_size, void* d_ws, size_t ws_size,
                              hipStream_t stream) {
  const float* x  = (const float*)d_in[0];  // [4096,1024]
  const float* gw = (const float*)d_in[1];  // [1024,16]
  const float* gb = (const float*)d_in[2];  // [16]
  const float* pw = (const float*)d_in[3];  // [1024,1024,16]
  const float* pb = (const float*)d_in[4];  // [1024,16]
  float* out = (float*)d_out;               // [4096,1024]

  const size_t w_bytes  = (size_t)NN * KK * sizeof(__hip_bfloat16);    // 33.6 MB
  const size_t xb_bytes = (size_t)BATCH * KK * sizeof(__hip_bfloat16); //  8.4 MB
  const size_t g_bytes  = (size_t)BATCH * NLEAF * sizeof(float);       //  0.26 MB

  if (ws_size >= w_bytes + xb_bytes + g_bytes) {
    __hip_bfloat16* W  = (__hip_bfloat16*)d_ws;
    __hip_bfloat16* xb = (__hip_bfloat16*)((char*)d_ws + w_bytes);
    float*          g  = (float*)((char*)d_ws + w_bytes + xb_bytes);

    prep_kernel<<<OUT_F + BATCH / 4, 256, 0, stream>>>(x, gw, gb, pw, g, xb, W);
    gemm_kernel<<<dim3(BATCH / TN, NN / TM), 256, 0, stream>>>(xb, W, g, pb, out);
  } else {
    float* g = (float*)d_ws;  // needs only 256 KB
    gate_kernel_fb<<<BATCH / 4, 256, 0, stream>>>(x, gw, gb, g);
    fallback_kernel<<<BATCH, 256, 0, stream>>>(x, pw, pb, g, out);
  }
}